// Round 3
// baseline (3229.026 us; speedup 1.0000x reference)
//
#include <hip/hip_runtime.h>
#include <stdint.h>

#define DEV static __device__ __forceinline__

typedef unsigned short u16;
typedef unsigned int u32;
typedef __attribute__((ext_vector_type(8))) u16 u16x8;
typedef __attribute__((ext_vector_type(8))) __bf16 bf16x8;
typedef __attribute__((ext_vector_type(4))) float f32x4;

// Problem constants
constexpr int Bc = 2, Sc = 2048, Dc = 768, Hc = 12;
constexpr int Vc = 50257, Fc = 3072;
constexpr int Mrows = Bc * Sc;      // 4096
constexpr int Vpad = 50304;         // V rounded up to 128
constexpr int QKVW = 3 * Dc;        // 2304

DEV u16 f2b(float f) {              // float -> bf16 bits, RNE
  u32 x = __float_as_uint(f);
  u32 r = (x + 0x7fffu + ((x >> 16) & 1u)) >> 16;
  return (u16)r;
}
DEV float b2f(u16 u) { return __uint_as_float(((u32)u) << 16); }

// ---------------------------------------------------------------------------
// 1) Embedding + positional encoding -> x_f32, x_bf16
//    pe[s,d] = sin/cos(s / 10000^(2d/D)), even d -> sin, odd d -> cos
// ---------------------------------------------------------------------------
__global__ __launch_bounds__(256) void embed_pos_kernel(
    const int* __restrict__ inp, const float* __restrict__ emb,
    float* __restrict__ x, u16* __restrict__ xb) {
  const int row = blockIdx.x;            // b*S + s
  const int s = row & (Sc - 1);
  const int tok = inp[row];
#pragma unroll
  for (int j = 0; j < 3; ++j) {
    const int d = threadIdx.x + j * 256;
    const float div = (float)s / powf(10000.0f, (2.0f * (float)d) / (float)Dc);
    const float pe = (d & 1) ? cosf(div) : sinf(div);
    const float v = emb[(size_t)tok * Dc + d] + pe;
    x[(size_t)row * Dc + d] = v;
    xb[(size_t)row * Dc + d] = f2b(v);
  }
}

// ---------------------------------------------------------------------------
// 2) Weight convert+transpose: W [K,N] f32 -> WT [Npad,K] bf16 (zero pad rows)
// ---------------------------------------------------------------------------
__global__ __launch_bounds__(256) void transpose_to_bf16(
    const float* __restrict__ W, u16* __restrict__ WT, int K, int N) {
  __shared__ float tile[32][33];         // +1 pad: conflict-free transpose
  const int tx = threadIdx.x;            // 0..31
  const int ty = threadIdx.y;            // 0..7
  const int n0 = blockIdx.x * 32;
  const int k0 = blockIdx.y * 32;
#pragma unroll
  for (int j = 0; j < 4; ++j) {
    const int n = n0 + tx;
    const int k = k0 + ty + j * 8;
    tile[ty + j * 8][tx] = (n < N) ? W[(size_t)k * N + n] : 0.f;
  }
  __syncthreads();
#pragma unroll
  for (int j = 0; j < 4; ++j) {
    const int n = n0 + ty + j * 8;       // output row (col of W)
    const int k = k0 + tx;               // output col
    WT[(size_t)n * K + k] = f2b(tile[tx][ty + j * 8]);
  }
}

// ---------------------------------------------------------------------------
// 3) W_o_eff: tile(out,H) @ W_o  ==  out @ (sum_h W_o[h*D:(h+1)*D, :])
//    Wo_eff[d][e] = sum_h Wo[h*D+d][e]; stored transposed bf16: WT[e][d]
// ---------------------------------------------------------------------------
__global__ __launch_bounds__(256) void woeff_kernel(
    const float* __restrict__ Wo, u16* __restrict__ WT) {
  const int idx = blockIdx.x * 256 + threadIdx.x;   // 768*768 total
  const int e = idx % Dc;                           // coalesced reads over e
  const int d = idx / Dc;
  float s = 0.f;
#pragma unroll
  for (int j = 0; j < Hc; ++j) s += Wo[((size_t)(j * Dc + d)) * Dc + e];
  WT[(size_t)e * Dc + d] = f2b(s);
}

// ---------------------------------------------------------------------------
// 4) bf16 MFMA GEMM, m97 structure: 128x128 tile, BK=64, 4 waves,
//    global_load_lds width 16, linear LDS [row][64].
//    C[m][n] = sum_k A[m][k]*BT[n][k] + bias[n] (+res) (relu) -> f32/bf16
// ---------------------------------------------------------------------------
template <bool RES, bool RELU, bool OUTF, bool OUTB>
__global__ __launch_bounds__(256, 2) void gemm_bf16(
    const u16* __restrict__ A, const u16* __restrict__ BT,
    const float* __restrict__ bias, const float* __restrict__ res,
    float* __restrict__ outF, u16* __restrict__ outB, int M, int N, int K) {
  __shared__ u16 Al[128 * 64];
  __shared__ u16 Bl[128 * 64];
  const int tid = threadIdx.x;
  const int lane = tid & 63;
  const int wv = tid >> 6;
  const int bm = blockIdx.y * 128;
  const int bn = blockIdx.x * 128;
  const int wr = (wv >> 1) * 64;
  const int wc = (wv & 1) * 64;

  f32x4 acc[4][4];
#pragma unroll
  for (int i = 0; i < 4; ++i)
#pragma unroll
    for (int j = 0; j < 4; ++j) {
      acc[i][j][0] = 0.f; acc[i][j][1] = 0.f;
      acc[i][j][2] = 0.f; acc[i][j][3] = 0.f;
    }

  // staging: each wave moves 32 rows of A and of BT per K-tile,
  // 4 x global_load_lds(16B) each; lane i -> row (i/8), 16B chunk (i%8)
  const int srow = wv * 32 + (lane >> 3);
  const int scol = (lane & 7) * 8;
  const u16* ga0 = A + (size_t)(bm + srow) * K + scol;
  const u16* gb0 = BT + (size_t)(bn + srow) * K + scol;
  u16* la0 = &Al[(wv * 32) * 64];
  u16* lb0 = &Bl[(wv * 32) * 64];

  for (int k0 = 0; k0 < K; k0 += 64) {
#pragma unroll
    for (int jj = 0; jj < 4; ++jj) {
      __builtin_amdgcn_global_load_lds(
          (const __attribute__((address_space(1))) void*)(ga0 + k0 + (size_t)jj * 8 * K),
          (__attribute__((address_space(3))) void*)(la0 + jj * 8 * 64), 16, 0, 0);
      __builtin_amdgcn_global_load_lds(
          (const __attribute__((address_space(1))) void*)(gb0 + k0 + (size_t)jj * 8 * K),
          (__attribute__((address_space(3))) void*)(lb0 + jj * 8 * 64), 16, 0, 0);
    }
    __syncthreads();   // drains vmcnt -> LDS tile ready
#pragma unroll
    for (int kk = 0; kk < 64; kk += 32) {
      const int ka = kk + (lane >> 4) * 8;
      bf16x8 af[4], bfr[4];
#pragma unroll
      for (int i = 0; i < 4; ++i)
        af[i] = __builtin_bit_cast(
            bf16x8, *(const u16x8*)&Al[(wr + i * 16 + (lane & 15)) * 64 + ka]);
#pragma unroll
      for (int j = 0; j < 4; ++j)
        bfr[j] = __builtin_bit_cast(
            bf16x8, *(const u16x8*)&Bl[(wc + j * 16 + (lane & 15)) * 64 + ka]);
#pragma unroll
      for (int i = 0; i < 4; ++i)
#pragma unroll
        for (int j = 0; j < 4; ++j)
          acc[i][j] = __builtin_amdgcn_mfma_f32_16x16x32_bf16(
              af[i], bfr[j], acc[i][j], 0, 0, 0);
    }
    __syncthreads();   // all reads done before next stage overwrites
  }

  // epilogue: C/D layout col=lane&15, row=(lane>>4)*4+reg  [m89/m91-verified]
  const int lr = (lane >> 4) * 4;
  const int lc = lane & 15;
#pragma unroll
  for (int j = 0; j < 4; ++j) {
    const int col = bn + wc + j * 16 + lc;
    if (col < N) {
      const float bv = bias[col];
#pragma unroll
      for (int i = 0; i < 4; ++i) {
#pragma unroll
        for (int r = 0; r < 4; ++r) {
          const int row = bm + wr + i * 16 + lr + r;
          float v = acc[i][j][r] + bv;
          if constexpr (RES) v += res[(size_t)row * N + col];
          if constexpr (RELU) v = fmaxf(v, 0.f);
          if constexpr (OUTF) outF[(size_t)row * N + col] = v;
          if constexpr (OUTB) outB[(size_t)row * N + col] = f2b(v);
        }
      }
    }
  }
}

// ---------------------------------------------------------------------------
// 5) Causal attention, online softmax. One wave per (b,h,q) row.
//    Lane j handles key k0+j in each 64-block; q and O kept in registers.
//    qkv rows: [4096][2304] bf16, q at h*64, k at 768+h*64, v at 1536+h*64.
// ---------------------------------------------------------------------------
__global__ __launch_bounds__(256, 1) void attention_kernel(
    const u16* __restrict__ qkv, u16* __restrict__ attn) {
  const int wid = blockIdx.x * 4 + (threadIdx.x >> 6);   // (b*H+h)*S + q
  const int lane = threadIdx.x & 63;
  const int q = wid & (Sc - 1);
  const int bh = wid >> 11;
  const int h = bh % Hc;
  const int b = bh / Hc;
  const size_t base = (size_t)b * Sc * QKVW;
  const u16* qp = qkv + base + (size_t)q * QKVW + h * 64;

  float qreg[64];
#pragma unroll
  for (int c = 0; c < 8; ++c) {
    const u16x8 t = *(const u16x8*)(qp + c * 8);
#pragma unroll
    for (int i = 0; i < 8; ++i) qreg[c * 8 + i] = b2f(t[i]) * 0.125f;  // 1/sqrt(64)
  }

  const u16* Kb = qkv + base + Dc + h * 64;
  const u16* Vb = qkv + base + 2 * Dc + h * 64;
  float m = -3.0e38f, lsum = 0.f;
  float outp[64];
#pragma unroll
  for (int d = 0; d < 64; ++d) outp[d] = 0.f;

  for (int k0 = 0; k0 <= q; k0 += 64) {
    const int j = k0 + lane;
    const int jj = (j <= q) ? j : 0;     // clamp to stay in-bounds
    const u16* kr = Kb + (size_t)jj * QKVW;
    float sc = 0.f;
#pragma unroll
    for (int c = 0; c < 8; ++c) {
      const u16x8 t = *(const u16x8*)(kr + c * 8);
#pragma unroll
      for (int i = 0; i < 8; ++i) sc = fmaf(qreg[c * 8 + i], b2f(t[i]), sc);
    }
    if (j > q) sc = -3.0e38f;
    float bmx = sc;
#pragma unroll
    for (int off = 32; off; off >>= 1) bmx = fmaxf(bmx, __shfl_xor(bmx, off, 64));
    const float mn = fmaxf(m, bmx);
    const float f = __expf(m - mn);
    const float p = (j <= q) ? __expf(sc - mn) : 0.f;
    lsum = lsum * f + p;
    m = mn;
    const u16* vr = Vb + (size_t)jj * QKVW;
#pragma unroll
    for (int c = 0; c < 8; ++c) {
      const u16x8 t = *(const u16x8*)(vr + c * 8);
#pragma unroll
      for (int i = 0; i < 8; ++i) {
        const int d = c * 8 + i;
        outp[d] = outp[d] * f + p * b2f(t[i]);
      }
    }
  }

  float lt = lsum;
#pragma unroll
  for (int off = 32; off; off >>= 1) lt += __shfl_xor(lt, off, 64);

  // butterfly transpose-reduce: lane l ends with sum over lanes of outp[l].
  // All indices static (rule #20).
#define TRSTEP(HALF)                                               \
  {                                                                \
    _Pragma("unroll")                                              \
    for (int i = 0; i < HALF; ++i) {                               \
      const float keep = (lane & HALF) ? outp[i + HALF] : outp[i]; \
      const float give = (lane & HALF) ? outp[i] : outp[i + HALF]; \
      outp[i] = keep + __shfl_xor(give, HALF, 64);                 \
    }                                                              \
  }
  TRSTEP(32) TRSTEP(16) TRSTEP(8) TRSTEP(4) TRSTEP(2) TRSTEP(1)
#undef TRSTEP

  const float o = outp[0] / lt;
  attn[(size_t)(b * Sc + q) * Dc + h * 64 + lane] = f2b(o);
}

// ---------------------------------------------------------------------------
// 6) LayerNorm over D=768. One wave per row; 12 floats/lane as 3 x float4.
// ---------------------------------------------------------------------------
template <bool WF>
__global__ __launch_bounds__(256) void layernorm_kernel(
    const float* __restrict__ in, const float* __restrict__ gw,
    const float* __restrict__ bw, float* __restrict__ outF,
    u16* __restrict__ outB) {
  const int row = blockIdx.x * 4 + (threadIdx.x >> 6);
  const int lane = threadIdx.x & 63;
  const float4* r = (const float4*)(in + (size_t)row * Dc);
  float4 v[3];
  float s = 0.f, ss = 0.f;
#pragma unroll
  for (int c = 0; c < 3; ++c) {
    v[c] = r[lane + c * 64];
    s += v[c].x + v[c].y + v[c].z + v[c].w;
    ss += v[c].x * v[c].x + v[c].y * v[c].y + v[c].z * v[c].z + v[c].w * v[c].w;
  }
#pragma unroll
  for (int off = 32; off; off >>= 1) {
    s += __shfl_xor(s, off, 64);
    ss += __shfl_xor(ss, off, 64);
  }
  const float mean = s * (1.f / (float)Dc);
  const float var = ss * (1.f / (float)Dc) - mean * mean;
  const float rstd = rsqrtf(fmaxf(var, 0.f) + 1e-5f);
  const float4* g4 = (const float4*)gw;
  const float4* b4 = (const float4*)bw;
#pragma unroll
  for (int c = 0; c < 3; ++c) {
    const int i4 = lane + c * 64;
    const float4 gg = g4[i4], bb = b4[i4];
    float4 o;
    o.x = (v[c].x - mean) * rstd * gg.x + bb.x;
    o.y = (v[c].y - mean) * rstd * gg.y + bb.y;
    o.z = (v[c].z - mean) * rstd * gg.z + bb.z;
    o.w = (v[c].w - mean) * rstd * gg.w + bb.w;
    if constexpr (WF) ((float4*)(outF + (size_t)row * Dc))[i4] = o;
    u16* ob = outB + (size_t)row * Dc + i4 * 4;
    ob[0] = f2b(o.x); ob[1] = f2b(o.y); ob[2] = f2b(o.z); ob[3] = f2b(o.w);
  }
}

// ---------------------------------------------------------------------------
// Orchestration
// ---------------------------------------------------------------------------
extern "C" void kernel_launch(void* const* d_in, const int* in_sizes, int n_in,
                              void* d_out, int out_size, void* d_ws,
                              size_t ws_size, hipStream_t stream) {
  const int* inputs = (const int*)d_in[0];
  const float* emb = (const float*)d_in[1];
  const float* W_qkv = (const float*)d_in[2];
  const float* b_qkv = (const float*)d_in[3];
  const float* W_o = (const float*)d_in[4];
  const float* b_o = (const float*)d_in[5];
  const float* ln1_g = (const float*)d_in[6];
  const float* ln1_b = (const float*)d_in[7];
  const float* W_ff1 = (const float*)d_in[8];
  const float* b_ff1 = (const float*)d_in[9];
  const float* W_ff2 = (const float*)d_in[10];
  const float* b_ff2 = (const float*)d_in[11];
  const float* ln2_g = (const float*)d_in[12];
  const float* ln2_b = (const float*)d_in[13];
  const float* W_out = (const float*)d_in[14];
  const float* b_out = (const float*)d_in[15];
  float* out = (float*)d_out;

  char* ws = (char*)d_ws;
  size_t off = 0;
  auto alloc = [&](size_t n) -> void* {
    void* p = ws + off;
    off += (n + 255) & ~(size_t)255;
    return p;
  };
  float* x_f = (float*)alloc((size_t)Mrows * Dc * 4);
  u16* x_b = (u16*)alloc((size_t)Mrows * Dc * 2);
  u16* qkv_b = (u16*)alloc((size_t)Mrows * QKVW * 2);
  u16* attn_b = (u16*)alloc((size_t)Mrows * Dc * 2);
  float* t_f = (float*)alloc((size_t)Mrows * Dc * 4);   // mha, then ffn-out
  float* h1_f = (float*)alloc((size_t)Mrows * Dc * 4);
  u16* h1_b = (u16*)alloc((size_t)Mrows * Dc * 2);
  u16* ff_b = (u16*)alloc((size_t)Mrows * Fc * 2);
  u16* h2_b = (u16*)alloc((size_t)Mrows * Dc * 2);
  u16* wt_qkv = (u16*)alloc((size_t)QKVW * Dc * 2);
  u16* wt_oe = (u16*)alloc((size_t)Dc * Dc * 2);
  u16* wt_f1 = (u16*)alloc((size_t)Fc * Dc * 2);
  u16* wt_f2 = (u16*)alloc((size_t)Dc * Fc * 2);
  u16* wt_out = (u16*)alloc((size_t)Vpad * Dc * 2);
  (void)ws_size; (void)n_in; (void)in_sizes; (void)out_size;

  const dim3 tb(32, 8);

  // weight prep (stream-ordered, all independent)
  transpose_to_bf16<<<dim3(QKVW / 32, Dc / 32), tb, 0, stream>>>(W_qkv, wt_qkv, Dc, QKVW);
  woeff_kernel<<<(Dc * Dc) / 256, 256, 0, stream>>>(W_o, wt_oe);
  transpose_to_bf16<<<dim3(Fc / 32, Dc / 32), tb, 0, stream>>>(W_ff1, wt_f1, Dc, Fc);
  transpose_to_bf16<<<dim3(Dc / 32, Fc / 32), tb, 0, stream>>>(W_ff2, wt_f2, Fc, Dc);
  transpose_to_bf16<<<dim3(Vpad / 32, Dc / 32), tb, 0, stream>>>(W_out, wt_out, Dc, Vc);

  // x = emb[tok] + pos
  embed_pos_kernel<<<Mrows, 256, 0, stream>>>(inputs, emb, x_f, x_b);

  // qkv = x @ W_qkv + b_qkv          [4096, 2304] bf16
  gemm_bf16<false, false, false, true><<<dim3(QKVW / 128, Mrows / 128), 256, 0, stream>>>(
      x_b, wt_qkv, b_qkv, nullptr, nullptr, qkv_b, Mrows, QKVW, Dc);

  // causal attention -> attn_b [4096, 768] bf16
  attention_kernel<<<(Bc * Hc * Sc) / 4, 256, 0, stream>>>(qkv_b, attn_b);

  // mha = attn @ Wo_eff + b_o + x    [4096, 768] f32
  gemm_bf16<true, false, true, false><<<dim3(Dc / 128, Mrows / 128), 256, 0, stream>>>(
      attn_b, wt_oe, b_o, x_f, t_f, nullptr, Mrows, Dc, Dc);

  // h1 = LN1(mha)
  layernorm_kernel<true><<<Mrows / 4, 256, 0, stream>>>(t_f, ln1_g, ln1_b, h1_f, h1_b);

  // ff = relu(h1 @ W_ff1 + b_ff1)    [4096, 3072] bf16
  gemm_bf16<false, true, false, true><<<dim3(Fc / 128, Mrows / 128), 256, 0, stream>>>(
      h1_b, wt_f1, b_ff1, nullptr, nullptr, ff_b, Mrows, Fc, Dc);

  // t = ff @ W_ff2 + b_ff2 + h1      [4096, 768] f32
  gemm_bf16<true, false, true, false><<<dim3(Dc / 128, Mrows / 128), 256, 0, stream>>>(
      ff_b, wt_f2, b_ff2, h1_f, t_f, nullptr, Mrows, Dc, Fc);

  // h2 = LN2(t)
  layernorm_kernel<false><<<Mrows / 4, 256, 0, stream>>>(t_f, ln2_g, ln2_b, nullptr, h2_b);

  // logits = h2 @ W_out + b_out      [4096, 50257] f32
  gemm_bf16<false, false, true, false><<<dim3(Vpad / 128, Mrows / 128), 256, 0, stream>>>(
      h2_b, wt_out, b_out, nullptr, out, nullptr, Mrows, Vc, Dc);
}